// Round 11
// baseline (242.344 us; speedup 1.0000x reference)
//
#include <hip/hip_runtime.h>
#include <hip/hip_fp16.h>

#define NN 80000
#define NE 1280000
#define F  64
#define BSH 9                        // 512 nodes per bucket
#define NB  157                      // ceil(NN / 512)
#define CAP 12288                    // per-bucket ebuf capacity (avg 8153)
#define EPB 5120                     // edges per partition block (128 B runs)
#define EPT 10                       // EPB / 512
#define PBLK (NE / EPB)              // 250

typedef _Float16 half_t;
typedef _Float16 half8 __attribute__((ext_vector_type(8)));
typedef float f32x4 __attribute__((ext_vector_type(4)));
typedef unsigned int uint_t;

__device__ __forceinline__ float2 h2f2(uint_t u) {
    __half2 h = *(__half2*)&u;
    return __half22float2(h);
}

__device__ __forceinline__ int ld_src(const int* __restrict__ idx, int e, int is64) {
    return is64 ? idx[2 * e] : idx[e];
}
__device__ __forceinline__ int ld_dst(const int* __restrict__ idx, int e, int is64) {
    return is64 ? idx[2 * NE + 2 * e] : idx[NE + e];
}

// ---------------------------------------------------------------------------
// Pass 1 (512 threads): partition edges into NB dst-buckets via LDS staging
// (cache-granular global writes, ~32-edge/128 B runs).
// ebuf[b*CAP + j] = (dstoff<<17) | src. Inline int64-vs-int32 sniff.
// ---------------------------------------------------------------------------
__global__ __launch_bounds__(512) void partition_kernel(
        const int* __restrict__ idx,
        int* __restrict__ bcur, int* __restrict__ ebuf) {
    __shared__ int cnt[NB];
    __shared__ int lbase[NB];
    __shared__ int gbase[NB];
    __shared__ int lds_val[EPB];
    __shared__ int lds_gaddr[EPB];
    __shared__ int is64_s;
    int tid = threadIdx.x;
    if (tid == 0) is64_s = 1;
    if (tid < NB) cnt[tid] = 0;
    __syncthreads();
    if (idx[2 * tid + 1] != 0) is64_s = 0;   // benign same-value race
    __syncthreads();
    int is64 = is64_s;
    int e0 = blockIdx.x * EPB;
    int val[EPT], br[EPT];
    #pragma unroll
    for (int j = 0; j < EPT; ++j) {
        int e = e0 + j * 512 + tid;
        int s = ld_src(idx, e, is64);
        int d = ld_dst(idx, e, is64);
        int b = d >> BSH;
        val[j] = ((d & ((1 << BSH) - 1)) << 17) | s;
        int r = atomicAdd(&cnt[b], 1);       // rank within (block, bucket)
        br[j] = (b << 13) | r;               // r < 5120 < 2^13
    }
    __syncthreads();
    if (tid < 64) {
        int carry = 0;
        for (int base = 0; base < NB; base += 64) {
            int i2 = base + tid;
            int v = (i2 < NB) ? cnt[i2] : 0;
            int incl = v;
            #pragma unroll
            for (int d2 = 1; d2 < 64; d2 <<= 1) {
                int t = __shfl_up(incl, d2, 64);
                if (tid >= d2) incl += t;
            }
            if (i2 < NB) lbase[i2] = carry + incl - v;
            carry += __shfl(incl, 63);
        }
    } else if (tid - 64 < NB) {
        int b = tid - 64;
        gbase[b] = atomicAdd(&bcur[b], cnt[b]);
    }
    __syncthreads();
    #pragma unroll
    for (int j = 0; j < EPT; ++j) {
        int b = br[j] >> 13, r = br[j] & 8191;
        int slot = lbase[b] + r;
        int g = gbase[b] + r;
        lds_val[slot]   = val[j];
        lds_gaddr[slot] = (g < CAP) ? (b * CAP + g) : -1;   // overflow guard
    }
    __syncthreads();
    for (int i = tid; i < EPB; i += 512) {
        int a = lds_gaddr[i];
        if (a >= 0) ebuf[a] = lds_val[i];    // ~32-edge (128 B) contiguous runs
    }
}

// ---------------------------------------------------------------------------
// Pass 2 (1024 threads): per-bucket LDS counting sort -> final CSR edata +
// row_ptr + dinv.
// ---------------------------------------------------------------------------
__global__ __launch_bounds__(1024) void bucket_sort_kernel(
        const int* __restrict__ bcur, const int* __restrict__ ebuf,
        int* __restrict__ edata, int* __restrict__ row_ptr,
        float* __restrict__ dinv) {
    __shared__ int cnt[512];
    __shared__ int off[512];
    __shared__ int lds_out[CAP];
    __shared__ int ebase_s;
    int b = blockIdx.x, tid = threadIdx.x;
    if (tid < 512) cnt[tid] = 0;
    if (tid < 64) {        // ebase = sum of min(bcur[j],CAP) for j<b
        int carry = 0;
        for (int base = 0; base < NB; base += 64) {
            int i2 = base + tid;
            int v = (i2 < NB) ? min(bcur[i2], CAP) : 0;
            int incl = v;
            #pragma unroll
            for (int d2 = 1; d2 < 64; d2 <<= 1) {
                int t = __shfl_up(incl, d2, 64);
                if (tid >= d2) incl += t;
            }
            if (i2 == b) ebase_s = carry + incl - v;
            carry += __shfl(incl, 63);
        }
    }
    __syncthreads();
    int bcnt = min(bcur[b], CAP);
    int ebase = ebase_s;
    const int* src = ebuf + b * CAP;
    for (int i = tid; i < bcnt; i += 1024)
        atomicAdd(&cnt[src[i] >> 17], 1);
    __syncthreads();
    if (tid < 64) {        // exclusive scan of 512 counters
        int carry = 0;
        #pragma unroll
        for (int base = 0; base < 512; base += 64) {
            int v = cnt[base + tid];
            int incl = v;
            #pragma unroll
            for (int d2 = 1; d2 < 64; d2 <<= 1) {
                int t = __shfl_up(incl, d2, 64);
                if (tid >= d2) incl += t;
            }
            off[base + tid] = carry + incl - v;
            carry += __shfl(incl, 63);
        }
    }
    __syncthreads();
    int n0 = b << BSH;
    if (tid < 512) {
        int n = n0 + tid;
        if (n < NN) {
            row_ptr[n] = ebase + off[tid];
            dinv[n] = rsqrtf((float)cnt[tid] + 1.f);
        } else if (n == NN) {
            row_ptr[NN] = ebase + off[tid];
        }
    }
    __syncthreads();
    for (int i = tid; i < bcnt; i += 1024) {
        int w = src[i];
        int pos = atomicAdd(&off[w >> 17], 1);
        lds_out[pos] = w & 0x1FFFF;
    }
    __syncthreads();
    for (int i = tid; i < bcnt; i += 1024)
        edata[ebase + i] = lds_out[i];
}

// y0 = fp16(X * dinv[row])
__global__ void prescale_kernel(const float* __restrict__ x, const float* __restrict__ dinv,
                                half_t* __restrict__ y) {
    int tid = blockIdx.x * blockDim.x + threadIdx.x;   // NN*16 threads
    if (tid >= NN * 16) return;
    int n = tid >> 4, q = tid & 15;
    float c = dinv[n];
    float4 v = ((const float4*)(x + (size_t)n * F))[q];
    half_t h[4] = { (half_t)(v.x * c), (half_t)(v.y * c),
                    (half_t)(v.z * c), (half_t)(v.w * c) };
    ((uint2*)(y + (size_t)n * F))[q] = *(uint2*)h;
}

// ---------------------------------------------------------------------------
// CSR gather v5 (fp16): TWO nodes per wave -> two independent memory chains
// interleaved (double MLP). Per node: 8 edge-slots x 8 lanes x uint4.
// agg[n] = fp16( dinv[n] * (y[n] + sum y[src]) ).
// ---------------------------------------------------------------------------
__global__ __launch_bounds__(256) void gather_kernel(const half_t* __restrict__ y,
        const int* __restrict__ edata, const int* __restrict__ row_ptr,
        half_t* __restrict__ agg) {
    int wv = threadIdx.x >> 6;
    int nA = blockIdx.x * 8 + wv * 2;      // grid = NN/8 exact; nodes nA, nA+1
    int lane = threadIdx.x & 63;
    int sub = lane >> 3;        // edge slot 0..7
    int fl  = lane & 7;         // uint4 index within 128 B feature row
    int pA0 = row_ptr[nA], pA1 = row_ptr[nA + 1], pB1 = row_ptr[nA + 2];
    int pB0 = pA1;
    float a[8], bb[8];
    #pragma unroll
    for (int i = 0; i < 8; ++i) { a[i] = 0.f; bb[i] = 0.f; }
    for (int baseA = pA0, baseB = pB0; baseA < pA1 || baseB < pB1;
         baseA += 32, baseB += 32) {
        int sA[4], sB[4]; float mA[4], mB[4];
        #pragma unroll
        for (int j = 0; j < 4; ++j) {
            int qA = baseA + j * 8 + sub;
            int qB = baseB + j * 8 + sub;
            sA[j] = edata[qA < pA1 ? qA : 0];
            sB[j] = edata[qB < pB1 ? qB : 0];
            mA[j] = (qA < pA1) ? 1.f : 0.f;
            mB[j] = (qB < pB1) ? 1.f : 0.f;
        }
        uint4 uA[4], uB[4];
        #pragma unroll
        for (int j = 0; j < 4; ++j) {
            uA[j] = ((const uint4*)(y + (size_t)sA[j] * F))[fl];
            uB[j] = ((const uint4*)(y + (size_t)sB[j] * F))[fl];
        }
        #pragma unroll
        for (int j = 0; j < 4; ++j) {
            float2 f0 = h2f2(uA[j].x), f1 = h2f2(uA[j].y);
            float2 f2 = h2f2(uA[j].z), f3 = h2f2(uA[j].w);
            a[0] = fmaf(mA[j], f0.x, a[0]); a[1] = fmaf(mA[j], f0.y, a[1]);
            a[2] = fmaf(mA[j], f1.x, a[2]); a[3] = fmaf(mA[j], f1.y, a[3]);
            a[4] = fmaf(mA[j], f2.x, a[4]); a[5] = fmaf(mA[j], f2.y, a[5]);
            a[6] = fmaf(mA[j], f3.x, a[6]); a[7] = fmaf(mA[j], f3.y, a[7]);
            float2 g0 = h2f2(uB[j].x), g1 = h2f2(uB[j].y);
            float2 g2 = h2f2(uB[j].z), g3 = h2f2(uB[j].w);
            bb[0] = fmaf(mB[j], g0.x, bb[0]); bb[1] = fmaf(mB[j], g0.y, bb[1]);
            bb[2] = fmaf(mB[j], g1.x, bb[2]); bb[3] = fmaf(mB[j], g1.y, bb[3]);
            bb[4] = fmaf(mB[j], g2.x, bb[4]); bb[5] = fmaf(mB[j], g2.y, bb[5]);
            bb[6] = fmaf(mB[j], g3.x, bb[6]); bb[7] = fmaf(mB[j], g3.y, bb[7]);
        }
    }
    // reduce 8 slots -> lanes 0..7 for both nodes
    #pragma unroll
    for (int i = 0; i < 8; ++i) {
        a[i]  += __shfl_down(a[i], 32);
        a[i]  += __shfl_down(a[i], 16);
        a[i]  += __shfl_down(a[i], 8);
        bb[i] += __shfl_down(bb[i], 32);
        bb[i] += __shfl_down(bb[i], 16);
        bb[i] += __shfl_down(bb[i], 8);
    }
    if (sub == 0) {
        float dvA = rsqrtf((float)(pA1 - pA0) + 1.f);
        uint4 us = ((const uint4*)(y + (size_t)nA * F))[fl];
        float2 s0 = h2f2(us.x), s1 = h2f2(us.y), s2 = h2f2(us.z), s3 = h2f2(us.w);
        half_t h[8] = {
            (half_t)(dvA * (a[0] + s0.x)), (half_t)(dvA * (a[1] + s0.y)),
            (half_t)(dvA * (a[2] + s1.x)), (half_t)(dvA * (a[3] + s1.y)),
            (half_t)(dvA * (a[4] + s2.x)), (half_t)(dvA * (a[5] + s2.y)),
            (half_t)(dvA * (a[6] + s3.x)), (half_t)(dvA * (a[7] + s3.y)) };
        ((uint4*)(agg + (size_t)nA * F))[fl] = *(uint4*)h;
        float dvB = rsqrtf((float)(pB1 - pB0) + 1.f);
        uint4 vs = ((const uint4*)(y + (size_t)(nA + 1) * F))[fl];
        float2 t0 = h2f2(vs.x), t1 = h2f2(vs.y), t2 = h2f2(vs.z), t3 = h2f2(vs.w);
        half_t h2[8] = {
            (half_t)(dvB * (bb[0] + t0.x)), (half_t)(dvB * (bb[1] + t0.y)),
            (half_t)(dvB * (bb[2] + t1.x)), (half_t)(dvB * (bb[3] + t1.y)),
            (half_t)(dvB * (bb[4] + t2.x)), (half_t)(dvB * (bb[5] + t2.y)),
            (half_t)(dvB * (bb[6] + t3.x)), (half_t)(dvB * (bb[7] + t3.y)) };
        ((uint4*)(agg + (size_t)(nA + 1) * F))[fl] = *(uint4*)h2;
    }
}

// ---------------------------------------------------------------------------
// MFMA GEMM: out = epilogue( A @ W + b ). A:[NN,64] fp16, 128 rows/block.
// ---------------------------------------------------------------------------
template <int RELU, int SCALE, int LAST>
__global__ __launch_bounds__(256) void gemm_mfma(
        const half_t* __restrict__ A, const float* __restrict__ W,
        const float* __restrict__ bias, const float* __restrict__ dinv,
        half_t* __restrict__ out_h, float* __restrict__ out_f32) {
    __shared__ half_t Wt[64][72];     // W^T fp16, padded (9216 B)
    __shared__ half_t xt[128][72];    // A tile (18432 B)
    int tid = threadIdx.x;
    for (int i = tid; i < 4096; i += 256) {
        int k = i >> 6, n2 = i & 63;
        Wt[n2][k] = (half_t)W[i];
    }
    int n0 = blockIdx.x * 128;        // grid = NN/128 exact
    for (int i2 = tid; i2 < 2048; i2 += 256) {
        int r = i2 >> 4, c = i2 & 15;
        ((uint2*)&xt[r][0])[c] = ((const uint2*)(A + (size_t)(n0 + r) * F))[c];
    }
    __syncthreads();
    int wv = tid >> 6, lane = tid & 63;
    int m = lane & 15, q = lane >> 4;
    #pragma unroll
    for (int rt = 0; rt < 2; ++rt) {
        int rbase = wv * 32 + rt * 16;
        const half_t* arow = &xt[rbase + m][q * 8];
        half8 A0 = *(const half8*)arow;
        half8 A1 = *(const half8*)(arow + 32);
        #pragma unroll
        for (int ct = 0; ct < 4; ++ct) {
            const half_t* brow = &Wt[ct * 16 + m][q * 8];
            half8 B0 = *(const half8*)brow;
            half8 B1 = *(const half8*)(brow + 32);
            f32x4 c = {0.f, 0.f, 0.f, 0.f};
            c = __builtin_amdgcn_mfma_f32_16x16x32_f16(A0, B0, c, 0, 0, 0);
            c = __builtin_amdgcn_mfma_f32_16x16x32_f16(A1, B1, c, 0, 0, 0);
            float bv = bias[ct * 16 + m];          // col = ct*16 + (lane&15)
            #pragma unroll
            for (int r = 0; r < 4; ++r) {
                int row = n0 + rbase + q * 4 + r;  // C/D: row = quad*4 + reg
                float v = c[r] + bv;
                if (RELU) v = fmaxf(v, 0.f);
                if (SCALE) v *= dinv[row];
                int col = ct * 16 + m;
                if (LAST) out_f32[(size_t)row * F + col] = v;
                else      out_h[(size_t)row * F + col] = (half_t)v;
            }
        }
    }
}

extern "C" void kernel_launch(void* const* d_in, const int* in_sizes, int n_in,
                              void* d_out, int out_size, void* d_ws, size_t ws_size,
                              hipStream_t stream) {
    const float* X  = (const float*)d_in[0];
    const int*  idx = (const int*)d_in[1];
    const float* W1 = (const float*)d_in[2];
    const float* b1 = (const float*)d_in[3];
    const float* W2 = (const float*)d_in[4];
    const float* b2 = (const float*)d_in[5];
    const float* W3 = (const float*)d_in[6];
    const float* b3 = (const float*)d_in[7];
    float* out = (float*)d_out;

    char* ws = (char*)d_ws;
    int*    bcur    = (int*)(ws + 256);                 // NB ints
    int*    row_ptr = (int*)(ws + 1024);                // NN+1 ints
    float*  dinv    = (float*)(ws + 321280);            // NN floats
    int*    edata   = (int*)(ws + 641536);              // NE ints (final CSR)
    half_t* ybufA   = (half_t*)(ws + 5761536);          // [NN,64] fp16
    half_t* ybufB   = (half_t*)(ws + 16001536);         // [NN,64] fp16 (agg)
    int*    ebuf    = (int*)(ws + 26241536);            // NB*CAP ints (7.7 MB)
    // total ws use ~34 MB

    hipMemsetAsync(bcur, 0, NB * sizeof(int), stream);
    partition_kernel<<<PBLK, 512, 0, stream>>>(idx, bcur, ebuf);
    bucket_sort_kernel<<<NB, 1024, 0, stream>>>(bcur, ebuf, edata, row_ptr, dinv);
    prescale_kernel<<<(NN * 16) / 256, 256, 0, stream>>>(X, dinv, ybufA);

    const int gBlocks = NN / 8;       // 10000
    const int mBlocks = NN / 128;     // 625

    // layer 1: agg(y0) -> ybufB ; y1 = fp16(dinv*relu(ybufB@W1+b1)) -> ybufA
    gather_kernel<<<gBlocks, 256, 0, stream>>>(ybufA, edata, row_ptr, ybufB);
    gemm_mfma<1, 1, 0><<<mBlocks, 256, 0, stream>>>(ybufB, W1, b1, dinv, ybufA, nullptr);
    // layer 2
    gather_kernel<<<gBlocks, 256, 0, stream>>>(ybufA, edata, row_ptr, ybufB);
    gemm_mfma<1, 1, 0><<<mBlocks, 256, 0, stream>>>(ybufB, W2, b2, dinv, ybufA, nullptr);
    // layer 3: fp32 output, no relu / no scale
    gather_kernel<<<gBlocks, 256, 0, stream>>>(ybufA, edata, row_ptr, ybufB);
    gemm_mfma<0, 0, 1><<<mBlocks, 256, 0, stream>>>(ybufB, W3, b3, dinv, nullptr, out);
}

// Round 12
// 226.751 us; speedup vs baseline: 1.0688x; 1.0688x over previous
//
#include <hip/hip_runtime.h>
#include <hip/hip_fp16.h>

#define NN 80000
#define NE 1280000
#define F  64
#define BSH 9                        // 512 nodes per bucket
#define NB  157                      // ceil(NN / 512)
#define CAP 12288                    // per-bucket ebuf capacity (avg 8153)
#define EPB 5120                     // edges per partition block (128 B runs)
#define EPT 10                       // EPB / 512
#define PBLK (NE / EPB)              // 250

typedef _Float16 half_t;
typedef _Float16 half8 __attribute__((ext_vector_type(8)));
typedef float f32x4 __attribute__((ext_vector_type(4)));
typedef unsigned int uint_t;

__device__ __forceinline__ float2 h2f2(uint_t u) {
    __half2 h = *(__half2*)&u;
    return __half22float2(h);
}

__device__ __forceinline__ int ld_src(const int* __restrict__ idx, int e, int is64) {
    return is64 ? idx[2 * e] : idx[e];
}
__device__ __forceinline__ int ld_dst(const int* __restrict__ idx, int e, int is64) {
    return is64 ? idx[2 * NE + 2 * e] : idx[NE + e];
}

// ---------------------------------------------------------------------------
// Pass 1 (512 threads): partition edges into NB dst-buckets via LDS staging
// (cache-granular global writes, ~32-edge/128 B runs).
// ebuf[b*CAP + j] = (dstoff<<17) | src. Inline int64-vs-int32 sniff.
// ---------------------------------------------------------------------------
__global__ __launch_bounds__(512) void partition_kernel(
        const int* __restrict__ idx,
        int* __restrict__ bcur, int* __restrict__ ebuf) {
    __shared__ int cnt[NB];
    __shared__ int lbase[NB];
    __shared__ int gbase[NB];
    __shared__ int lds_val[EPB];
    __shared__ int lds_gaddr[EPB];
    __shared__ int is64_s;
    int tid = threadIdx.x;
    if (tid == 0) is64_s = 1;
    if (tid < NB) cnt[tid] = 0;
    __syncthreads();
    if (idx[2 * tid + 1] != 0) is64_s = 0;   // benign same-value race
    __syncthreads();
    int is64 = is64_s;
    int e0 = blockIdx.x * EPB;
    int val[EPT], br[EPT];
    #pragma unroll
    for (int j = 0; j < EPT; ++j) {
        int e = e0 + j * 512 + tid;
        int s = ld_src(idx, e, is64);
        int d = ld_dst(idx, e, is64);
        int b = d >> BSH;
        val[j] = ((d & ((1 << BSH) - 1)) << 17) | s;
        int r = atomicAdd(&cnt[b], 1);       // rank within (block, bucket)
        br[j] = (b << 13) | r;               // r < 5120 < 2^13
    }
    __syncthreads();
    if (tid < 64) {
        int carry = 0;
        for (int base = 0; base < NB; base += 64) {
            int i2 = base + tid;
            int v = (i2 < NB) ? cnt[i2] : 0;
            int incl = v;
            #pragma unroll
            for (int d2 = 1; d2 < 64; d2 <<= 1) {
                int t = __shfl_up(incl, d2, 64);
                if (tid >= d2) incl += t;
            }
            if (i2 < NB) lbase[i2] = carry + incl - v;
            carry += __shfl(incl, 63);
        }
    } else if (tid - 64 < NB) {
        int b = tid - 64;
        gbase[b] = atomicAdd(&bcur[b], cnt[b]);
    }
    __syncthreads();
    #pragma unroll
    for (int j = 0; j < EPT; ++j) {
        int b = br[j] >> 13, r = br[j] & 8191;
        int slot = lbase[b] + r;
        int g = gbase[b] + r;
        lds_val[slot]   = val[j];
        lds_gaddr[slot] = (g < CAP) ? (b * CAP + g) : -1;   // overflow guard
    }
    __syncthreads();
    for (int i = tid; i < EPB; i += 512) {
        int a = lds_gaddr[i];
        if (a >= 0) ebuf[a] = lds_val[i];    // ~32-edge (128 B) contiguous runs
    }
}

// ---------------------------------------------------------------------------
// Pass 2 (1024 threads): per-bucket LDS counting sort -> final CSR edata +
// row_ptr + dinv.
// ---------------------------------------------------------------------------
__global__ __launch_bounds__(1024) void bucket_sort_kernel(
        const int* __restrict__ bcur, const int* __restrict__ ebuf,
        int* __restrict__ edata, int* __restrict__ row_ptr,
        float* __restrict__ dinv) {
    __shared__ int cnt[512];
    __shared__ int off[512];
    __shared__ int lds_out[CAP];
    __shared__ int ebase_s;
    int b = blockIdx.x, tid = threadIdx.x;
    if (tid < 512) cnt[tid] = 0;
    if (tid < 64) {        // ebase = sum of min(bcur[j],CAP) for j<b
        int carry = 0;
        for (int base = 0; base < NB; base += 64) {
            int i2 = base + tid;
            int v = (i2 < NB) ? min(bcur[i2], CAP) : 0;
            int incl = v;
            #pragma unroll
            for (int d2 = 1; d2 < 64; d2 <<= 1) {
                int t = __shfl_up(incl, d2, 64);
                if (tid >= d2) incl += t;
            }
            if (i2 == b) ebase_s = carry + incl - v;
            carry += __shfl(incl, 63);
        }
    }
    __syncthreads();
    int bcnt = min(bcur[b], CAP);
    int ebase = ebase_s;
    const int* src = ebuf + b * CAP;
    for (int i = tid; i < bcnt; i += 1024)
        atomicAdd(&cnt[src[i] >> 17], 1);
    __syncthreads();
    if (tid < 64) {        // exclusive scan of 512 counters
        int carry = 0;
        #pragma unroll
        for (int base = 0; base < 512; base += 64) {
            int v = cnt[base + tid];
            int incl = v;
            #pragma unroll
            for (int d2 = 1; d2 < 64; d2 <<= 1) {
                int t = __shfl_up(incl, d2, 64);
                if (tid >= d2) incl += t;
            }
            off[base + tid] = carry + incl - v;
            carry += __shfl(incl, 63);
        }
    }
    __syncthreads();
    int n0 = b << BSH;
    if (tid < 512) {
        int n = n0 + tid;
        if (n < NN) {
            row_ptr[n] = ebase + off[tid];
            dinv[n] = rsqrtf((float)cnt[tid] + 1.f);
        } else if (n == NN) {
            row_ptr[NN] = ebase + off[tid];
        }
    }
    __syncthreads();
    for (int i = tid; i < bcnt; i += 1024) {
        int w = src[i];
        int pos = atomicAdd(&off[w >> 17], 1);
        lds_out[pos] = w & 0x1FFFF;
    }
    __syncthreads();
    for (int i = tid; i < bcnt; i += 1024)
        edata[ebase + i] = lds_out[i];
}

// y0 = fp16(X * dinv[row])
__global__ void prescale_kernel(const float* __restrict__ x, const float* __restrict__ dinv,
                                half_t* __restrict__ y) {
    int tid = blockIdx.x * blockDim.x + threadIdx.x;   // NN*16 threads
    if (tid >= NN * 16) return;
    int n = tid >> 4, q = tid & 15;
    float c = dinv[n];
    float4 v = ((const float4*)(x + (size_t)n * F))[q];
    half_t h[4] = { (half_t)(v.x * c), (half_t)(v.y * c),
                    (half_t)(v.z * c), (half_t)(v.w * c) };
    ((uint2*)(y + (size_t)n * F))[q] = *(uint2*)h;
}

// ---------------------------------------------------------------------------
// CSR gather v6 (fp16): one node per wave; 8 edge-slots x 8 lanes x uint4.
// Adaptive tail: only ceil(rem/8) of the 4 slot-group loads are issued
// (wave-uniform branches) -> ~37% fewer row-load instructions vs v4.
// Self-row load hoisted to overlap the edge loop.
// agg[n] = fp16( dinv[n] * (y[n] + sum y[src]) ).
// ---------------------------------------------------------------------------
__global__ __launch_bounds__(256) void gather_kernel(const half_t* __restrict__ y,
        const int* __restrict__ edata, const int* __restrict__ row_ptr,
        half_t* __restrict__ agg) {
    int n = blockIdx.x * 4 + (threadIdx.x >> 6);   // grid = NN/4 exact
    int lane = threadIdx.x & 63;
    int sub = lane >> 3;        // edge slot 0..7
    int fl  = lane & 7;         // uint4 index within 128 B feature row
    int p0 = row_ptr[n], p1 = row_ptr[n + 1];
    uint4 us = ((const uint4*)(y + (size_t)n * F))[fl];   // self row (early)
    float a[8];
    #pragma unroll
    for (int i = 0; i < 8; ++i) a[i] = 0.f;
    int p = p0;
    // full unmasked 32-edge batches (deg > 32 is ~1e-5 of nodes)
    while (p + 32 <= p1) {
        int s[4];
        #pragma unroll
        for (int j = 0; j < 4; ++j) s[j] = edata[p + j * 8 + sub];
        uint4 u[4];
        #pragma unroll
        for (int j = 0; j < 4; ++j)
            u[j] = ((const uint4*)(y + (size_t)s[j] * F))[fl];
        #pragma unroll
        for (int j = 0; j < 4; ++j) {
            float2 f0 = h2f2(u[j].x), f1 = h2f2(u[j].y);
            float2 f2 = h2f2(u[j].z), f3 = h2f2(u[j].w);
            a[0] += f0.x; a[1] += f0.y; a[2] += f1.x; a[3] += f1.y;
            a[4] += f2.x; a[5] += f2.y; a[6] += f3.x; a[7] += f3.y;
        }
        p += 32;
    }
    int rem = p1 - p;           // 0..31
    if (rem > 0) {
        int s[4]; float m[4];
        #pragma unroll
        for (int j = 0; j < 4; ++j) {
            int q = p + j * 8 + sub;
            s[j] = edata[q < p1 ? q : p1 - 1];
            m[j] = (q < p1) ? 1.f : 0.f;
        }
        uint4 u[4];
        u[0] = ((const uint4*)(y + (size_t)s[0] * F))[fl];
        if (rem > 8)  u[1] = ((const uint4*)(y + (size_t)s[1] * F))[fl];
        if (rem > 16) u[2] = ((const uint4*)(y + (size_t)s[2] * F))[fl];
        if (rem > 24) u[3] = ((const uint4*)(y + (size_t)s[3] * F))[fl];
        {
            float2 f0 = h2f2(u[0].x), f1 = h2f2(u[0].y);
            float2 f2 = h2f2(u[0].z), f3 = h2f2(u[0].w);
            a[0] = fmaf(m[0], f0.x, a[0]); a[1] = fmaf(m[0], f0.y, a[1]);
            a[2] = fmaf(m[0], f1.x, a[2]); a[3] = fmaf(m[0], f1.y, a[3]);
            a[4] = fmaf(m[0], f2.x, a[4]); a[5] = fmaf(m[0], f2.y, a[5]);
            a[6] = fmaf(m[0], f3.x, a[6]); a[7] = fmaf(m[0], f3.y, a[7]);
        }
        if (rem > 8) {
            float2 f0 = h2f2(u[1].x), f1 = h2f2(u[1].y);
            float2 f2 = h2f2(u[1].z), f3 = h2f2(u[1].w);
            a[0] = fmaf(m[1], f0.x, a[0]); a[1] = fmaf(m[1], f0.y, a[1]);
            a[2] = fmaf(m[1], f1.x, a[2]); a[3] = fmaf(m[1], f1.y, a[3]);
            a[4] = fmaf(m[1], f2.x, a[4]); a[5] = fmaf(m[1], f2.y, a[5]);
            a[6] = fmaf(m[1], f3.x, a[6]); a[7] = fmaf(m[1], f3.y, a[7]);
        }
        if (rem > 16) {
            float2 f0 = h2f2(u[2].x), f1 = h2f2(u[2].y);
            float2 f2 = h2f2(u[2].z), f3 = h2f2(u[2].w);
            a[0] = fmaf(m[2], f0.x, a[0]); a[1] = fmaf(m[2], f0.y, a[1]);
            a[2] = fmaf(m[2], f1.x, a[2]); a[3] = fmaf(m[2], f1.y, a[3]);
            a[4] = fmaf(m[2], f2.x, a[4]); a[5] = fmaf(m[2], f2.y, a[5]);
            a[6] = fmaf(m[2], f3.x, a[6]); a[7] = fmaf(m[2], f3.y, a[7]);
        }
        if (rem > 24) {
            float2 f0 = h2f2(u[3].x), f1 = h2f2(u[3].y);
            float2 f2 = h2f2(u[3].z), f3 = h2f2(u[3].w);
            a[0] = fmaf(m[3], f0.x, a[0]); a[1] = fmaf(m[3], f0.y, a[1]);
            a[2] = fmaf(m[3], f1.x, a[2]); a[3] = fmaf(m[3], f1.y, a[3]);
            a[4] = fmaf(m[3], f2.x, a[4]); a[5] = fmaf(m[3], f2.y, a[5]);
            a[6] = fmaf(m[3], f3.x, a[6]); a[7] = fmaf(m[3], f3.y, a[7]);
        }
    }
    // reduce 8 slots -> lanes 0..7
    #pragma unroll
    for (int i = 0; i < 8; ++i) {
        a[i] += __shfl_down(a[i], 32);
        a[i] += __shfl_down(a[i], 16);
        a[i] += __shfl_down(a[i], 8);
    }
    if (sub == 0) {
        float dv = rsqrtf((float)(p1 - p0) + 1.f);
        float2 s0 = h2f2(us.x), s1 = h2f2(us.y), s2 = h2f2(us.z), s3 = h2f2(us.w);
        half_t h[8] = {
            (half_t)(dv * (a[0] + s0.x)), (half_t)(dv * (a[1] + s0.y)),
            (half_t)(dv * (a[2] + s1.x)), (half_t)(dv * (a[3] + s1.y)),
            (half_t)(dv * (a[4] + s2.x)), (half_t)(dv * (a[5] + s2.y)),
            (half_t)(dv * (a[6] + s3.x)), (half_t)(dv * (a[7] + s3.y)) };
        ((uint4*)(agg + (size_t)n * F))[fl] = *(uint4*)h;
    }
}

// ---------------------------------------------------------------------------
// MFMA GEMM: out = epilogue( A @ W + b ). A:[NN,64] fp16, 128 rows/block.
// ---------------------------------------------------------------------------
template <int RELU, int SCALE, int LAST>
__global__ __launch_bounds__(256) void gemm_mfma(
        const half_t* __restrict__ A, const float* __restrict__ W,
        const float* __restrict__ bias, const float* __restrict__ dinv,
        half_t* __restrict__ out_h, float* __restrict__ out_f32) {
    __shared__ half_t Wt[64][72];     // W^T fp16, padded (9216 B)
    __shared__ half_t xt[128][72];    // A tile (18432 B)
    int tid = threadIdx.x;
    for (int i = tid; i < 4096; i += 256) {
        int k = i >> 6, n2 = i & 63;
        Wt[n2][k] = (half_t)W[i];
    }
    int n0 = blockIdx.x * 128;        // grid = NN/128 exact
    for (int i2 = tid; i2 < 2048; i2 += 256) {
        int r = i2 >> 4, c = i2 & 15;
        ((uint2*)&xt[r][0])[c] = ((const uint2*)(A + (size_t)(n0 + r) * F))[c];
    }
    __syncthreads();
    int wv = tid >> 6, lane = tid & 63;
    int m = lane & 15, q = lane >> 4;
    #pragma unroll
    for (int rt = 0; rt < 2; ++rt) {
        int rbase = wv * 32 + rt * 16;
        const half_t* arow = &xt[rbase + m][q * 8];
        half8 A0 = *(const half8*)arow;
        half8 A1 = *(const half8*)(arow + 32);
        #pragma unroll
        for (int ct = 0; ct < 4; ++ct) {
            const half_t* brow = &Wt[ct * 16 + m][q * 8];
            half8 B0 = *(const half8*)brow;
            half8 B1 = *(const half8*)(brow + 32);
            f32x4 c = {0.f, 0.f, 0.f, 0.f};
            c = __builtin_amdgcn_mfma_f32_16x16x32_f16(A0, B0, c, 0, 0, 0);
            c = __builtin_amdgcn_mfma_f32_16x16x32_f16(A1, B1, c, 0, 0, 0);
            float bv = bias[ct * 16 + m];          // col = ct*16 + (lane&15)
            #pragma unroll
            for (int r = 0; r < 4; ++r) {
                int row = n0 + rbase + q * 4 + r;  // C/D: row = quad*4 + reg
                float v = c[r] + bv;
                if (RELU) v = fmaxf(v, 0.f);
                if (SCALE) v *= dinv[row];
                int col = ct * 16 + m;
                if (LAST) out_f32[(size_t)row * F + col] = v;
                else      out_h[(size_t)row * F + col] = (half_t)v;
            }
        }
    }
}

extern "C" void kernel_launch(void* const* d_in, const int* in_sizes, int n_in,
                              void* d_out, int out_size, void* d_ws, size_t ws_size,
                              hipStream_t stream) {
    const float* X  = (const float*)d_in[0];
    const int*  idx = (const int*)d_in[1];
    const float* W1 = (const float*)d_in[2];
    const float* b1 = (const float*)d_in[3];
    const float* W2 = (const float*)d_in[4];
    const float* b2 = (const float*)d_in[5];
    const float* W3 = (const float*)d_in[6];
    const float* b3 = (const float*)d_in[7];
    float* out = (float*)d_out;

    char* ws = (char*)d_ws;
    int*    bcur    = (int*)(ws + 256);                 // NB ints
    int*    row_ptr = (int*)(ws + 1024);                // NN+1 ints
    float*  dinv    = (float*)(ws + 321280);            // NN floats
    int*    edata   = (int*)(ws + 641536);              // NE ints (final CSR)
    half_t* ybufA   = (half_t*)(ws + 5761536);          // [NN,64] fp16
    half_t* ybufB   = (half_t*)(ws + 16001536);         // [NN,64] fp16 (agg)
    int*    ebuf    = (int*)(ws + 26241536);            // NB*CAP ints (7.7 MB)
    // total ws use ~34 MB

    hipMemsetAsync(bcur, 0, NB * sizeof(int), stream);
    partition_kernel<<<PBLK, 512, 0, stream>>>(idx, bcur, ebuf);
    bucket_sort_kernel<<<NB, 1024, 0, stream>>>(bcur, ebuf, edata, row_ptr, dinv);
    prescale_kernel<<<(NN * 16) / 256, 256, 0, stream>>>(X, dinv, ybufA);

    const int gBlocks = NN / 4;       // 20000
    const int mBlocks = NN / 128;     // 625

    // layer 1: agg(y0) -> ybufB ; y1 = fp16(dinv*relu(ybufB@W1+b1)) -> ybufA
    gather_kernel<<<gBlocks, 256, 0, stream>>>(ybufA, edata, row_ptr, ybufB);
    gemm_mfma<1, 1, 0><<<mBlocks, 256, 0, stream>>>(ybufB, W1, b1, dinv, ybufA, nullptr);
    // layer 2
    gather_kernel<<<gBlocks, 256, 0, stream>>>(ybufA, edata, row_ptr, ybufB);
    gemm_mfma<1, 1, 0><<<mBlocks, 256, 0, stream>>>(ybufB, W2, b2, dinv, ybufA, nullptr);
    // layer 3: fp32 output, no relu / no scale
    gather_kernel<<<gBlocks, 256, 0, stream>>>(ybufA, edata, row_ptr, ybufB);
    gemm_mfma<0, 0, 1><<<mBlocks, 256, 0, stream>>>(ybufB, W3, b3, dinv, nullptr, out);
}